// Round 7
// baseline (51.052 us; speedup 1.0000x reference)
//
#include <hip/hip_runtime.h>

// PPO model loss — R14: fused kernel at FULL occupancy (1 row/block, 1024 blocks).
// R13 measured 42us @ Occupancy 37%, VALUBusy 12%, 1.25 TB/s — latency-bound
// at HALF occupancy. RPB=2/512 blocks was over-conservative: at 40 VGPR +
// 512B LDS the HW fits 4 blocks x 8 waves = 32 waves/CU, so grid 1024
// (= 4 x 256 CUs) is fully co-resident. R14: RPB=1, NBLK=1024,
// __launch_bounds__(512,8) (8 waves/SIMD -> VGPR<=64; compiler was at 40).
// Barrier scaled to 1024 arrivals: tree 128x8 -> 16x8 -> 2x8 -> 2, all
// RELAXED + ONE release fence (producer) / ONE acquire fence (consumer) —
// R12/R13 lesson: agent-ordered ops emit buffer_wbl2/inv per op; fence-once.
// Release broadcast: 128 relaxed flag lines, <=8 pollers each, s_sleep poll.
//
//   phase A: 1 row/block (8 waves = 8 segments), wave-scan + LDS-compose,
//            row stats -> blkS1/blkS2[bid]; RETAIN v[], L[], carry in regs.
//   bar1   : tree arrival + broadcast release.
//   phase B: each block reduces 1024 (s1,s2) pairs (grid-stride, 2/thread)
//            -> mean/invstd; loss from RETAINED state + va/lp/ol/mk streams;
//            per-block partial triple via plain stores.
//   finalize: one block reduces 1024 partial triples -> scalar loss.
//
// ws: [0)      288 lines x 32 ints (128B stride) barrier state (~36 KB)
//     [65536)  blkS1[1024], blkS2[1024], part[3*1024] doubles

static constexpr int T_DIM = 4096;
static constexpr int SEG   = 512;          // elements per segment (one wave)
static constexpr int NSEG  = 8;            // segments per row
static constexpr int CH    = 8;            // elements per lane
static constexpr int BT    = 512;          // 8 waves per block
static constexpr int NW    = 8;
static constexpr int NBLK  = 1024;         // one row per block

#define CDEC 0.95f
#define CLIPR 0.2f
#define CLIPV 0.2f
#define AGENT __HIP_MEMORY_SCOPE_AGENT

// barrier state: counters 0..146, flags 160..287 (128B-strided lines)
static constexpr int LSTRIDE  = 32;             // 128 B between lines
static constexpr int BAR_INTS = 288 * LSTRIDE;

__device__ __forceinline__ void bar_arrive(int* base, int bid) {
  // thread 0 of each block; caller's global stores must precede
  __builtin_amdgcn_fence(__ATOMIC_RELEASE, "agent");   // ONE wbl2
  const int l0 = bid & 127;                            // 128 lines, 8 each
  if (__hip_atomic_fetch_add(base + l0 * LSTRIDE, 1,
                             __ATOMIC_RELAXED, AGENT) == 7) {
    const int l1 = 128 + (l0 >> 3);                    // 16 lines, 8 each
    if (__hip_atomic_fetch_add(base + l1 * LSTRIDE, 1,
                               __ATOMIC_RELAXED, AGENT) == 7) {
      const int l2 = 144 + (l0 >> 6);                  // 2 lines, 8 each
      if (__hip_atomic_fetch_add(base + l2 * LSTRIDE, 1,
                                 __ATOMIC_RELAXED, AGENT) == 7) {
        if (__hip_atomic_fetch_add(base + 146 * LSTRIDE, 1,
                                   __ATOMIC_RELAXED, AGENT) == 1) {
          // relaxed broadcast: 128 flag lines, <=8 pollers each
#pragma unroll
          for (int i = 0; i < 128; ++i)
            __hip_atomic_store(base + (160 + i) * LSTRIDE, 1,
                               __ATOMIC_RELAXED, AGENT);
        }
      }
    }
  }
}
__device__ __forceinline__ void bar_wait(int* base, int bid) {
  int* flag = base + (160 + (bid & 127)) * LSTRIDE;
  while (__hip_atomic_load(flag, __ATOMIC_RELAXED, AGENT) == 0)
    __builtin_amdgcn_s_sleep(2);
  __builtin_amdgcn_fence(__ATOMIC_ACQUIRE, "agent");   // ONE buffer_inv
}

__device__ __forceinline__ double wave_sum_d(double v) {
#pragma unroll
  for (int d = 32; d > 0; d >>= 1) v += __shfl_down(v, d);
  return v;
}
// inclusive suffix scan of affine (L, M) across the 64-lane wave
__device__ __forceinline__ void wave_suffix(float& sL, float& sM, int lane) {
#pragma unroll
  for (int d = 1; d < 64; d <<= 1) {
    float oL = __shfl_down(sL, d);
    float oM = __shfl_down(sM, d);
    if (lane + d < 64) { sL += sM * oL; sM *= oM; }
  }
}

// ---------------- init: zero barrier state ---------------------------------
__global__ __launch_bounds__(256) void init_kernel(int* bar) {
  for (int i = threadIdx.x; i < BAR_INTS; i += 256) bar[i] = 0;
}

// ---------------- fused kernel (plain launch, capacity-guaranteed) ---------
__global__ __launch_bounds__(BT, 8) void coop_kernel(
    const float* __restrict__ logprobs,
    const float* __restrict__ values,
    const float* __restrict__ old_logprobs,
    const float* __restrict__ old_values,
    const float* __restrict__ rewards,
    const int*   __restrict__ mask,
    int* __restrict__ bar1,
    double* __restrict__ blkS1, double* __restrict__ blkS2,
    double* __restrict__ part) {
  const int tid  = threadIdx.x;
  const int lane = tid & 63;
  const int seg  = tid >> 6;          // wave id == segment id within row
  const int bid  = blockIdx.x;        // == row
  const float c  = CDEC;

  __shared__ float  segL[NSEG], segM[NSEG], segC[NSEG];
  __shared__ double red2[2][NW];
  __shared__ double red3[3][NW];
  __shared__ float  sc[2];

  float cCH;
  { float pw = 1.f;
#pragma unroll
    for (int i = 0; i < CH; ++i) pw *= c;
    cCH = pw; }

  // ---------------- phase A: row stats, retain scan state ------------------
  float vK[CH], LK[CH], carry;
  const long base = ((long)bid * NSEG + seg) * SEG + (long)lane * CH;
  {
    const float4 rv0 = *(const float4*)(rewards + base);
    const float4 rv1 = *(const float4*)(rewards + base + 4);
    const float4 vv0 = *(const float4*)(old_values + base);
    const float4 vv1 = *(const float4*)(old_values + base + 4);

    float v9[CH + 1], rw[CH];
    v9[0] = vv0.x; v9[1] = vv0.y; v9[2] = vv0.z; v9[3] = vv0.w;
    v9[4] = vv1.x; v9[5] = vv1.y; v9[6] = vv1.z; v9[7] = vv1.w;
    rw[0] = rv0.x; rw[1] = rv0.y; rw[2] = rv0.z; rw[3] = rv0.w;
    rw[4] = rv1.x; rw[5] = rv1.y; rw[6] = rv1.z; rw[7] = rv1.w;
    float nv = __shfl_down(v9[0], 1);
    if (lane == 63) nv = (seg == NSEG - 1) ? 0.f : old_values[base + CH];
    v9[CH] = nv;

    // local suffix scan (zero carry-in)
    LK[CH - 1] = rw[CH - 1] + v9[CH] - v9[CH - 1];
#pragma unroll
    for (int j = CH - 2; j >= 0; --j)
      LK[j] = (rw[j] + v9[j + 1] - v9[j]) + c * LK[j + 1];
#pragma unroll
    for (int j = 0; j < CH; ++j) vK[j] = v9[j];

    float sL = LK[0], sM = cCH;
    wave_suffix(sL, sM, lane);
    float nLc = __shfl_down(sL, 1);
    float nMc = __shfl_down(sM, 1);
    if (lane == 63) { nLc = 0.f; nMc = 1.f; }

    if (lane == 0) { segL[seg] = sL; segM[seg] = sM; }
    __syncthreads();
    if (tid == 0) {
      float C = 0.f;
#pragma unroll
      for (int s = NSEG - 1; s >= 0; --s) { segC[s] = C; C = segL[s] + segM[s] * C; }
    }
    __syncthreads();
    carry = nLc + nMc * segC[seg];

    float s1 = 0.f, s2 = 0.f;
    { float cpw = 1.f;
#pragma unroll
      for (int j = CH - 1; j >= 0; --j) {
        cpw *= c;                        // c^(CH-j)
        const float A = LK[j] + carry * cpw;
        s1 += A; s2 += A * A;
      } }

    double d1 = wave_sum_d((double)s1);
    double d2 = wave_sum_d((double)s2);
    if (lane == 0) { red2[0][seg] = d1; red2[1][seg] = d2; }
    __syncthreads();
    if (tid == 0) {
      double s1d = 0.0, s2d = 0.0;
#pragma unroll
      for (int w = 0; w < NW; ++w) { s1d += red2[0][w]; s2d += red2[1][w]; }
      blkS1[bid] = s1d;                  // ordered by release fence in arrive
      blkS2[bid] = s2d;
      bar_arrive(bar1, bid);
      bar_wait(bar1, bid);
    }
  }
  __syncthreads();

  // ---------------- phase B: mean/invstd + loss ----------------------------
  // plain loads: ordered after bar_wait's acquire fence + syncthreads
  double t1 = 0.0, t2 = 0.0;
  for (int i = tid; i < NBLK; i += BT) { t1 += blkS1[i]; t2 += blkS2[i]; }
  t1 = wave_sum_d(t1);
  t2 = wave_sum_d(t2);
  if (lane == 0) { red2[0][seg] = t1; red2[1][seg] = t2; }
  __syncthreads();
  if (tid == 0) {
    double S1 = 0.0, S2 = 0.0;
#pragma unroll
    for (int w = 0; w < NW; ++w) { S1 += red2[0][w]; S2 += red2[1][w]; }
    const double dn  = (double)NBLK * T_DIM;
    const double mean = S1 / dn;
    const double var  = (S2 - S1 * S1 / dn) / (dn - 1.0);
    sc[0] = (float)mean;
    sc[1] = (float)(1.0 / sqrt(var + 1e-8));
  }
  __syncthreads();
  const float meanf = sc[0], invstdf = sc[1];

  float vf_s = 0.f, pg_s = 0.f, n_s = 0.f;
  {
    const float4 va0 = *(const float4*)(values + base);
    const float4 va1 = *(const float4*)(values + base + 4);
    const float4 lp0 = *(const float4*)(logprobs + base);
    const float4 lp1 = *(const float4*)(logprobs + base + 4);
    const float4 ol0 = *(const float4*)(old_logprobs + base);
    const float4 ol1 = *(const float4*)(old_logprobs + base + 4);
    const int4   mk0 = *(const int4*)(mask + base);
    const int4   mk1 = *(const int4*)(mask + base + 4);

    float va[CH], lp[CH], ol[CH];
    int mk[CH];
    va[0] = va0.x; va[1] = va0.y; va[2] = va0.z; va[3] = va0.w;
    va[4] = va1.x; va[5] = va1.y; va[6] = va1.z; va[7] = va1.w;
    lp[0] = lp0.x; lp[1] = lp0.y; lp[2] = lp0.z; lp[3] = lp0.w;
    lp[4] = lp1.x; lp[5] = lp1.y; lp[6] = lp1.z; lp[7] = lp1.w;
    ol[0] = ol0.x; ol[1] = ol0.y; ol[2] = ol0.z; ol[3] = ol0.w;
    ol[4] = ol1.x; ol[5] = ol1.y; ol[6] = ol1.z; ol[7] = ol1.w;
    mk[0] = mk0.x; mk[1] = mk0.y; mk[2] = mk0.z; mk[3] = mk0.w;
    mk[4] = mk1.x; mk[5] = mk1.y; mk[6] = mk1.z; mk[7] = mk1.w;

    float cpw = 1.f;
#pragma unroll
    for (int j = CH - 1; j >= 0; --j) {
      cpw *= c;                          // c^(CH-j)
      const float A   = LK[j] + carry * cpw;
      const float mf  = (float)mk[j];
      const float ret = A + vK[j];
      const float vc2 = fminf(fmaxf(va[j], vK[j] - CLIPV), vK[j] + CLIPV);
      const float d1  = va[j] - ret, d2 = vc2 - ret;
      vf_s += fmaxf(d1 * d1, d2 * d2) * mf;
      const float ratio = expf((lp[j] - ol[j]) * mf);
      const float a     = (A - meanf) * invstdf;
      const float p1    = -a * ratio;
      const float p2    = -a * fminf(fmaxf(ratio, 1.f - CLIPR), 1.f + CLIPR);
      pg_s += fmaxf(p1, p2) * mf;
      n_s  += mf;
    }
  }

  double r0 = wave_sum_d((double)vf_s);
  double r1 = wave_sum_d((double)pg_s);
  double r2 = wave_sum_d((double)n_s);
  if (lane == 0) { red3[0][seg] = r0; red3[1][seg] = r1; red3[2][seg] = r2; }
  __syncthreads();
  if (tid == 0) {
    double b0 = 0.0, b1 = 0.0, b2 = 0.0;
#pragma unroll
    for (int w = 0; w < NW; ++w) { b0 += red3[0][w]; b1 += red3[1][w]; b2 += red3[2][w]; }
    part[3 * bid + 0] = b0;              // plain stores; kernel boundary
    part[3 * bid + 1] = b1;              // guarantees visibility to finalize
    part[3 * bid + 2] = b2;
  }
}

// ---------------- finalize: reduce per-block partials ----------------------
__global__ __launch_bounds__(1024) void finalize_kernel(
    const double* __restrict__ part, int nblk, float* __restrict__ out) {
  const int tid  = threadIdx.x;
  const int lane = tid & 63;
  const int wave = tid >> 6;
  double vf = 0.0, pg = 0.0, n = 0.0;
  for (int i = tid; i < nblk; i += 1024) {
    vf += part[3 * i + 0];
    pg += part[3 * i + 1];
    n  += part[3 * i + 2];
  }
  __shared__ double red[3][16];
  vf = wave_sum_d(vf); pg = wave_sum_d(pg); n = wave_sum_d(n);
  if (lane == 0) { red[0][wave] = vf; red[1][wave] = pg; red[2][wave] = n; }
  __syncthreads();
  if (tid == 0) {
    double t0 = 0.0, t1 = 0.0, t2 = 0.0;
#pragma unroll
    for (int w = 0; w < 16; ++w) {
      t0 += red[0][w]; t1 += red[1][w]; t2 += red[2][w];
    }
    out[0] = (float)(t1 / t2 + 0.5 * t0 / t2);   // VF_COEF = 1.0
  }
}

extern "C" void kernel_launch(void* const* d_in, const int* in_sizes, int n_in,
                              void* d_out, int out_size, void* d_ws, size_t ws_size,
                              hipStream_t stream) {
  const float* logprobs     = (const float*)d_in[0];
  const float* values       = (const float*)d_in[1];
  const float* old_logprobs = (const float*)d_in[2];
  const float* old_values   = (const float*)d_in[3];
  const float* rewards      = (const float*)d_in[4];
  const int*   mask         = (const int*)d_in[5];

  char* p = (char*)d_ws;
  int* bar1 = (int*)p;
  double* blkS1 = (double*)(p + 65536);
  double* blkS2 = blkS1 + NBLK;
  double* part  = blkS2 + NBLK;
  float* outp   = (float*)d_out;

  init_kernel<<<1, 256, 0, stream>>>(bar1);
  coop_kernel<<<NBLK, BT, 0, stream>>>(logprobs, values, old_logprobs,
                                       old_values, rewards, mask, bar1,
                                       blkS1, blkS2, part);
  finalize_kernel<<<1, 1024, 0, stream>>>(part, NBLK, outp);
}

// Round 14
// 37.624 us; speedup vs baseline: 1.3569x; 1.3569x over previous
//
#include <hip/hip_runtime.h>

// PPO model loss — R21: bit-exact hold of R9 (verified: 38.0us, passed,
// zero device atomics). SIXTH consecutive pre-execution infra failure on
// the same wedged container ("stiff-dense-novel-robot", dead since R15's
// spin hang). R20 was the control: even this known-good kernel fails with
// "connection closed while sending first message" — the harness never
// pushes files; kernel content is exonerated. Strategy: keep the verified
// kernel on the wire every round until the broker recycles the container.
// On recovery: re-anchor at ~38us + fresh counters, then run the queued
// R16 last-block-ticket experiment (predicted -4-6us) as a clean
// single-variable change on the same container.
//
//  pass1   : row-per-block. Wave-scan each segment, LDS-compose 8 affines,
//            sum(adv), sum(adv^2) -> one (s1,s2) double pair per row.
//  pass2   : row-per-block. Rescan (rewards/old_values L3-warm), recompute
//            carries in-block; whitening mean/invstd from the 1024 row pairs
//            reduced redundantly per-block (16KB L2/L3, hidden under the 10
//            in-flight global float4 loads). Per-block (vf,pg,n) partials
//            via plain stores.
//  finalize: one block reduces 3*nrows doubles -> scalar loss.
//
// ws layout: [64)                 nrows doubles rowS1
//            [64+8*nrows)         nrows doubles rowS2
//            [64+16*nrows)        3*nrows doubles part

static constexpr int T_DIM = 4096;
static constexpr int SEG   = 512;           // elements per segment (one wave)
static constexpr int NSEG  = T_DIM / SEG;   // 8 segments per row
static constexpr int CH    = 8;             // elements per lane
static constexpr int BT    = 512;           // 8 waves: one block == one row
static constexpr int NW    = BT / 64;       // 8 == NSEG

static_assert(NW == NSEG, "block must cover exactly one row");

#define CDEC 0.95f
#define CLIPR 0.2f
#define CLIPV 0.2f

__device__ __forceinline__ double wave_sum_d(double v) {
#pragma unroll
  for (int d = 32; d > 0; d >>= 1) v += __shfl_down(v, d);
  return v;
}
// inclusive suffix scan of affine (L, M) across the 64-lane wave
__device__ __forceinline__ void wave_suffix(float& sL, float& sM, int lane) {
#pragma unroll
  for (int d = 1; d < 64; d <<= 1) {
    float oL = __shfl_down(sL, d);
    float oM = __shfl_down(sM, d);
    if (lane + d < 64) { sL += sM * oL; sM *= oM; }
  }
}

// ---------------- pass1: row stats (sum A, sum A^2) ------------------------
__global__ __launch_bounds__(BT) void pass1_kernel(
    const float* __restrict__ old_values,
    const float* __restrict__ rewards,
    double* __restrict__ rowS1,
    double* __restrict__ rowS2) {
  const int tid  = threadIdx.x;
  const int lane = tid & 63;
  const int seg  = tid >> 6;
  const int row  = blockIdx.x;
  const float c  = CDEC;
  const long base = ((long)row * NSEG + seg) * SEG + (long)lane * CH;

  const float4 rv0 = *(const float4*)(rewards + base);
  const float4 rv1 = *(const float4*)(rewards + base + 4);
  const float4 vv0 = *(const float4*)(old_values + base);
  const float4 vv1 = *(const float4*)(old_values + base + 4);

  float v[CH + 1], rw[CH];
  v[0] = vv0.x; v[1] = vv0.y; v[2] = vv0.z; v[3] = vv0.w;
  v[4] = vv1.x; v[5] = vv1.y; v[6] = vv1.z; v[7] = vv1.w;
  rw[0] = rv0.x; rw[1] = rv0.y; rw[2] = rv0.z; rw[3] = rv0.w;
  rw[4] = rv1.x; rw[5] = rv1.y; rw[6] = rv1.z; rw[7] = rv1.w;
  float nv = __shfl_down(v[0], 1);
  if (lane == 63) nv = (seg == NSEG - 1) ? 0.f : old_values[base + CH];
  v[CH] = nv;

  float cCH;
  { float pw = 1.f;
#pragma unroll
    for (int i = 0; i < CH; ++i) pw *= c;
    cCH = pw; }

  // local suffix scan (zero carry-in)
  float L[CH];
  L[CH - 1] = rw[CH - 1] + v[CH] - v[CH - 1];
#pragma unroll
  for (int j = CH - 2; j >= 0; --j)
    L[j] = (rw[j] + v[j + 1] - v[j]) + c * L[j + 1];

  float sL = L[0], sM = cCH;
  wave_suffix(sL, sM, lane);
  float nLc = __shfl_down(sL, 1);
  float nMc = __shfl_down(sM, 1);
  if (lane == 63) { nLc = 0.f; nMc = 1.f; }

  __shared__ float segL[NSEG], segM[NSEG], segC[NSEG];
  __shared__ double red[2][NW];
  if (lane == 0) { segL[seg] = sL; segM[seg] = sM; }
  __syncthreads();
  if (tid == 0) {
    float C = 0.f;
#pragma unroll
    for (int s = NSEG - 1; s >= 0; --s) { segC[s] = C; C = segL[s] + segM[s] * C; }
  }
  __syncthreads();
  const float carry = nLc + nMc * segC[seg];

  float s1 = 0.f, s2 = 0.f;
  { float cpw = 1.f;
#pragma unroll
    for (int j = CH - 1; j >= 0; --j) {
      cpw *= c;                          // c^(CH-j)
      const float A = L[j] + carry * cpw;
      s1 += A; s2 += A * A;
    } }

  double d1 = wave_sum_d((double)s1);
  double d2 = wave_sum_d((double)s2);
  if (lane == 0) { red[0][seg] = d1; red[1][seg] = d2; }
  __syncthreads();
  if (tid == 0) {
    double t1 = 0.0, t2 = 0.0;
#pragma unroll
    for (int w = 0; w < NW; ++w) { t1 += red[0][w]; t2 += red[1][w]; }
    rowS1[row] = t1; rowS2[row] = t2;
  }
}

// ---------------- pass2: loss (rescan, per-block partial stores) -----------
__global__ __launch_bounds__(BT) void pass2_kernel(
    const float* __restrict__ logprobs,
    const float* __restrict__ values,
    const float* __restrict__ old_logprobs,
    const float* __restrict__ old_values,
    const float* __restrict__ rewards,
    const int*   __restrict__ mask,
    const double* __restrict__ rowS1,
    const double* __restrict__ rowS2,
    double* __restrict__ part,
    int nrows) {
  const int tid  = threadIdx.x;
  const int lane = tid & 63;
  const int seg  = tid >> 6;
  const int row  = blockIdx.x;
  const float c  = CDEC;
  const long base = ((long)row * NSEG + seg) * SEG + (long)lane * CH;

  const float4 rv0 = *(const float4*)(rewards + base);
  const float4 rv1 = *(const float4*)(rewards + base + 4);
  const float4 vv0 = *(const float4*)(old_values + base);
  const float4 vv1 = *(const float4*)(old_values + base + 4);
  const float4 va0 = *(const float4*)(values + base);
  const float4 va1 = *(const float4*)(values + base + 4);
  const float4 lp0 = *(const float4*)(logprobs + base);
  const float4 lp1 = *(const float4*)(logprobs + base + 4);
  const float4 ol0 = *(const float4*)(old_logprobs + base);
  const float4 ol1 = *(const float4*)(old_logprobs + base + 4);
  const int4  mk0  = *(const int4*)(mask + base);
  const int4  mk1  = *(const int4*)(mask + base + 4);

  // whitening-constant reduce: independent of the loads above, hides under
  // their latency. ~2 L2/L3 loads per thread.
  double t1 = 0.0, t2 = 0.0;
  for (int i = tid; i < nrows; i += BT) { t1 += rowS1[i]; t2 += rowS2[i]; }
  t1 = wave_sum_d(t1);
  t2 = wave_sum_d(t2);

  __shared__ float segL[NSEG], segM[NSEG], segC[NSEG];
  __shared__ double redS[2][NW];
  __shared__ double red3[3][NW];
  __shared__ float sc[2];
  if (lane == 0) { redS[0][seg] = t1; redS[1][seg] = t2; }

  float v[CH + 1], rw[CH], va[CH], lp[CH], ol[CH];
  int mk[CH];
  v[0] = vv0.x; v[1] = vv0.y; v[2] = vv0.z; v[3] = vv0.w;
  v[4] = vv1.x; v[5] = vv1.y; v[6] = vv1.z; v[7] = vv1.w;
  rw[0] = rv0.x; rw[1] = rv0.y; rw[2] = rv0.z; rw[3] = rv0.w;
  rw[4] = rv1.x; rw[5] = rv1.y; rw[6] = rv1.z; rw[7] = rv1.w;
  va[0] = va0.x; va[1] = va0.y; va[2] = va0.z; va[3] = va0.w;
  va[4] = va1.x; va[5] = va1.y; va[6] = va1.z; va[7] = va1.w;
  lp[0] = lp0.x; lp[1] = lp0.y; lp[2] = lp0.z; lp[3] = lp0.w;
  lp[4] = lp1.x; lp[5] = lp1.y; lp[6] = lp1.z; lp[7] = lp1.w;
  ol[0] = ol0.x; ol[1] = ol0.y; ol[2] = ol0.z; ol[3] = ol0.w;
  ol[4] = ol1.x; ol[5] = ol1.y; ol[6] = ol1.z; ol[7] = ol1.w;
  mk[0] = mk0.x; mk[1] = mk0.y; mk[2] = mk0.z; mk[3] = mk0.w;
  mk[4] = mk1.x; mk[5] = mk1.y; mk[6] = mk1.z; mk[7] = mk1.w;

  float nv = __shfl_down(v[0], 1);
  if (lane == 63) nv = (seg == NSEG - 1) ? 0.f : old_values[base + CH];
  v[CH] = nv;

  float cCH;
  { float pw = 1.f;
#pragma unroll
    for (int i = 0; i < CH; ++i) pw *= c;
    cCH = pw; }

  float L[CH];
  L[CH - 1] = rw[CH - 1] + v[CH] - v[CH - 1];
#pragma unroll
  for (int j = CH - 2; j >= 0; --j)
    L[j] = (rw[j] + v[j + 1] - v[j]) + c * L[j + 1];

  float sL = L[0], sM = cCH;
  wave_suffix(sL, sM, lane);
  float nLc = __shfl_down(sL, 1);
  float nMc = __shfl_down(sM, 1);
  if (lane == 63) { nLc = 0.f; nMc = 1.f; }

  if (lane == 0) { segL[seg] = sL; segM[seg] = sM; }
  __syncthreads();
  if (tid == 0) {
    float C = 0.f;
#pragma unroll
    for (int s = NSEG - 1; s >= 0; --s) { segC[s] = C; C = segL[s] + segM[s] * C; }
    double S1 = 0.0, S2 = 0.0;
#pragma unroll
    for (int w = 0; w < NW; ++w) { S1 += redS[0][w]; S2 += redS[1][w]; }
    const double dn  = (double)nrows * (double)T_DIM;
    const double mean = S1 / dn;
    const double var  = (S2 - S1 * S1 / dn) / (dn - 1.0);
    sc[0] = (float)mean;
    sc[1] = (float)(1.0 / sqrt(var + 1e-8));
  }
  __syncthreads();
  const float carry   = nLc + nMc * segC[seg];
  const float meanf   = sc[0];
  const float invstdf = sc[1];

  float vf_s = 0.f, pg_s = 0.f, n_s = 0.f;
  { float cpw = 1.f;
#pragma unroll
    for (int j = CH - 1; j >= 0; --j) {
      cpw *= c;                          // c^(CH-j)
      const float A   = L[j] + carry * cpw;
      const float mf  = (float)mk[j];
      const float ret = A + v[j];
      const float vc2 = fminf(fmaxf(va[j], v[j] - CLIPV), v[j] + CLIPV);
      const float d1  = va[j] - ret, d2 = vc2 - ret;
      vf_s += fmaxf(d1 * d1, d2 * d2) * mf;
      const float ratio = expf((lp[j] - ol[j]) * mf);
      const float a     = (A - meanf) * invstdf;
      const float p1    = -a * ratio;
      const float p2    = -a * fminf(fmaxf(ratio, 1.f - CLIPR), 1.f + CLIPR);
      pg_s += fmaxf(p1, p2) * mf;
      n_s  += mf;
    } }

  double r0 = wave_sum_d((double)vf_s);
  double r1 = wave_sum_d((double)pg_s);
  double r2 = wave_sum_d((double)n_s);
  if (lane == 0) { red3[0][seg] = r0; red3[1][seg] = r1; red3[2][seg] = r2; }
  __syncthreads();
  if (tid == 0) {
    double b0 = 0.0, b1 = 0.0, b2 = 0.0;
#pragma unroll
    for (int w = 0; w < NW; ++w) { b0 += red3[0][w]; b1 += red3[1][w]; b2 += red3[2][w]; }
    part[3 * blockIdx.x + 0] = b0;   // plain stores — zero atomics
    part[3 * blockIdx.x + 1] = b1;
    part[3 * blockIdx.x + 2] = b2;
  }
}

// ---------------- finalize: reduce per-block partials ----------------------
__global__ __launch_bounds__(1024) void finalize_kernel(
    const double* __restrict__ part, int nblk, float* __restrict__ out) {
  const int tid  = threadIdx.x;
  const int lane = tid & 63;
  const int wave = tid >> 6;
  double vf = 0.0, pg = 0.0, n = 0.0;
  for (int i = tid; i < nblk; i += 1024) {
    vf += part[3 * i + 0];
    pg += part[3 * i + 1];
    n  += part[3 * i + 2];
  }
  __shared__ double red[3][16];
  vf = wave_sum_d(vf); pg = wave_sum_d(pg); n = wave_sum_d(n);
  if (lane == 0) { red[0][wave] = vf; red[1][wave] = pg; red[2][wave] = n; }
  __syncthreads();
  if (tid == 0) {
    double t0 = 0.0, t1 = 0.0, t2 = 0.0;
#pragma unroll
    for (int w = 0; w < 16; ++w) {
      t0 += red[0][w]; t1 += red[1][w]; t2 += red[2][w];
    }
    out[0] = (float)(t1 / t2 + 0.5 * t0 / t2);   // VF_COEF = 1.0
  }
}

extern "C" void kernel_launch(void* const* d_in, const int* in_sizes, int n_in,
                              void* d_out, int out_size, void* d_ws, size_t ws_size,
                              hipStream_t stream) {
  const float* logprobs     = (const float*)d_in[0];
  const float* values       = (const float*)d_in[1];
  const float* old_logprobs = (const float*)d_in[2];
  const float* old_values   = (const float*)d_in[3];
  const float* rewards      = (const float*)d_in[4];
  const int*   mask         = (const int*)d_in[5];

  const long total = (long)in_sizes[0];
  const int  nrows = (int)(total / T_DIM);

  char* p = (char*)d_ws;
  double* rowS1 = (double*)(p + 64);
  double* rowS2 = rowS1 + nrows;
  double* part  = rowS2 + nrows;

  pass1_kernel<<<nrows, BT, 0, stream>>>(old_values, rewards, rowS1, rowS2);
  pass2_kernel<<<nrows, BT, 0, stream>>>(logprobs, values, old_logprobs,
                                         old_values, rewards, mask, rowS1,
                                         rowS2, part, nrows);
  finalize_kernel<<<1, 1024, 0, stream>>>(part, nrows, (float*)d_out);
}